// Round 4
// baseline (810.485 us; speedup 1.0000x reference)
//
#include <hip/hip_runtime.h>

#define Dm 128
#define Bn 16
#define TZ 8
#define TY 8
#define TX 16            // tile width in w; each thread owns a w-pair
#define HZ (TZ + 2)      // 10
#define HY (TY + 2)      // 10
#define HX (TX + 2)      // 18 valid columns
#define HXP 20           // LDS row stride (words)
#define TILE_N (HZ * HY * HXP)          // 2000 used words
#define TILE_A 2048                     // padded slab: NT*NLOAD writes land in-slab
#define NT 512
#define NLOAD (TILE_A / NT)             // 4
#define VOX (Dm * Dm * Dm)
#define BCH 2            // batches per staged chunk
#define NCH (Bn / BCH)   // 8 chunks

__device__ __forceinline__ void gload_lds4(const void* g, void* l) {
  __builtin_amdgcn_global_load_lds(
      (const __attribute__((address_space(1))) void*)g,
      (__attribute__((address_space(3))) void*)l,
      4, 0, 0);
}

__device__ __forceinline__ int iclamp(int v, int lo, int hi) {
  return v < lo ? lo : (v > hi ? hi : v);
}

extern "C" __global__ void __launch_bounds__(512, 8)   // force 4 blocks/CU (VGPR<=64)
fused3d(const float* __restrict__ img, const float* __restrict__ x,
        const float* __restrict__ Wf, const float* __restrict__ bfp,
        float* __restrict__ out)
{
  __shared__ float sX[2][BCH][TILE_A];   // 32768 B -> 4 blocks/CU by LDS

  const int tid = threadIdx.x;
  const int tx = tid & 7;          // w-pair index 0..7
  const int ty = (tid >> 3) & 7;   // h 0..7
  const int tz = tid >> 6;         // d 0..7 (== wave id)
  const int w0 = blockIdx.x * TX;
  const int h0 = blockIdx.y * TY;
  const int d0 = blockIdx.z * TZ;

  // ---- staging descriptors: CLAMPED coords, unconditional loads (no masks).
  // Halo correctness is restored by zeroing boundary K-taps below.
  int goff[NLOAD];
#pragma unroll
  for (int k = 0; k < NLOAD; ++k) {
    int i  = tid + k * NT;         // 0..2047, all land inside the padded slab
    int r  = i / HXP;
    int c  = i - r * HXP;          // 0..19 (c>=18 pad, clamped harmlessly)
    int zz = r / HY;
    int yy = r - zz * HY;
    int gd = iclamp(d0 + zz - 1, 0, Dm - 1);
    int gh = iclamp(h0 + yy - 1, 0, Dm - 1);
    int gw = iclamp(w0 + c  - 1, 0, Dm - 1);
    goff[k] = (gd * Dm + gh) * Dm + gw;
  }

  const int wbase = tid & ~63;     // wave-uniform LDS base for global_load_lds

  // ---- stage chunk 0 (batches 0,1) async direct-to-LDS; overlaps K compute
#pragma unroll
  for (int j = 0; j < BCH; ++j) {
    const float* xb = x + (size_t)j * VOX;
#pragma unroll
    for (int k = 0; k < NLOAD; ++k)
      gload_lds4(xb + goff[k], &sX[0][j][k * NT + wbase]);
  }

  // ---- K[27] per voxel-pair, row-streaming (keeps peak VGPR ~60):
  // image window uses ZERO padding (reference conv SAME semantics).
  float K0[27], K1[27];
#pragma unroll
  for (int o = 0; o < 27; ++o) { K0[o] = bfp[o]; K1[o] = bfp[o]; }

#pragma unroll
  for (int rr = 0; rr < 9; ++rr) {
    const int dz = rr / 3, dy = rr - 3 * (rr / 3);
    const int gd = d0 + tz + dz - 1;
    const int gh = h0 + ty + dy - 1;
    const bool rowok = ((unsigned)gd < Dm) & ((unsigned)gh < Dm);
    const float* rp = img + ((size_t)gd * Dm + gh) * Dm;
    float v0, v1, v2, v3;
    {
      int gw = w0 + 2 * tx - 1;
      v0 = (rowok && (unsigned)(gw + 0) < Dm) ? rp[gw + 0] : 0.f;
      v1 = (rowok && (unsigned)(gw + 1) < Dm) ? rp[gw + 1] : 0.f;
      v2 = (rowok && (unsigned)(gw + 2) < Dm) ? rp[gw + 2] : 0.f;
      v3 = (rowok && (unsigned)(gw + 3) < Dm) ? rp[gw + 3] : 0.f;
    }
#pragma unroll
    for (int o = 0; o < 27; ++o) {
      const float wa = Wf[o * 27 + rr * 3 + 0];   // wave-uniform s_loads
      const float wb = Wf[o * 27 + rr * 3 + 1];
      const float wc = Wf[o * 27 + rr * 3 + 2];
      K0[o] = fmaf(wa, v0, fmaf(wb, v1, fmaf(wc, v2, K0[o])));
      K1[o] = fmaf(wa, v1, fmaf(wb, v2, fmaf(wc, v3, K1[o])));
    }
  }

  // ---- zero boundary taps: tap*x_pad(0) in the reference == 0*x_clamped here
  const int od = d0 + tz, oh = h0 + ty, ow = w0 + 2 * tx;
  {
    float md[3], mh[3], mw0[3], mw1[3];
#pragma unroll
    for (int t = 0; t < 3; ++t) {
      md[t]  = ((unsigned)(od + t - 1) < Dm) ? 1.f : 0.f;
      mh[t]  = ((unsigned)(oh + t - 1) < Dm) ? 1.f : 0.f;
      mw0[t] = ((unsigned)(ow + t - 1) < Dm) ? 1.f : 0.f;
      mw1[t] = ((unsigned)(ow + t)     < Dm) ? 1.f : 0.f;
    }
#pragma unroll
    for (int o = 0; o < 27; ++o) {
      const int di = o / 9, dj = (o / 3) % 3, dk = o % 3;
      const float m = md[di] * mh[dj];
      K0[o] *= m * mw0[dk];
      K1[o] *= m * mw1[dk];
    }
  }

  __syncthreads();   // chunk 0 staged (vmcnt drained) & visible

  const size_t obase = (((size_t)od) * Dm + oh) * Dm + ow;

  // ---- chunk loop: 8 chunks x 2 batches; prefetch next chunk first (T14)
  for (int ch = 0; ch < NCH; ++ch) {
    const int cur = ch & 1;

    if (ch + 1 < NCH) {
      const float* xc = x + (size_t)(ch + 1) * BCH * VOX;
#pragma unroll
      for (int j = 0; j < BCH; ++j) {
        const float* xb = xc + (size_t)j * VOX;
#pragma unroll
        for (int k = 0; k < NLOAD; ++k)
          gload_lds4(xb + goff[k], &sX[cur ^ 1][j][k * NT + wbase]);
      }
    }

#pragma unroll
    for (int j = 0; j < BCH; ++j) {
      const float* sxb = sX[cur][j];
      float acc0 = 0.f, acc1 = 0.f;
#pragma unroll
      for (int dz = 0; dz < 3; ++dz)
#pragma unroll
        for (int dy = 0; dy < 3; ++dy) {
          int base = ((tz + dz) * HY + (ty + dy)) * HXP + 2 * tx;
          float2 a  = *(const float2*)&sxb[base];
          float2 b2 = *(const float2*)&sxb[base + 2];
          int rr = dz * 3 + dy;
          acc0 = fmaf(K0[rr * 3 + 0], a.x,  acc0);
          acc0 = fmaf(K0[rr * 3 + 1], a.y,  acc0);
          acc0 = fmaf(K0[rr * 3 + 2], b2.x, acc0);
          acc1 = fmaf(K1[rr * 3 + 0], a.y,  acc1);
          acc1 = fmaf(K1[rr * 3 + 1], b2.x, acc1);
          acc1 = fmaf(K1[rr * 3 + 2], b2.y, acc1);
        }
      float2 st; st.x = acc0; st.y = acc1;
      *(float2*)&out[(size_t)(ch * BCH + j) * VOX + obase] = st;
    }

    __syncthreads();  // prefetched chunk complete + guards buffer reuse
  }
}

extern "C" void kernel_launch(void* const* d_in, const int* in_sizes, int n_in,
                              void* d_out, int out_size, void* d_ws, size_t ws_size,
                              hipStream_t stream) {
  const float* img = (const float*)d_in[0];
  const float* x   = (const float*)d_in[1];
  const float* Wf  = (const float*)d_in[2];
  const float* bf  = (const float*)d_in[3];
  float* out = (float*)d_out;
  dim3 grid(Dm / TX, Dm / TY, Dm / TZ);  // 8 x 16 x 16 = 2048 blocks
  hipLaunchKernelGGL(fused3d, grid, dim3(NT), 0, stream, img, x, Wf, bf, out);
}

// Round 5
// 121.096 us; speedup vs baseline: 6.6929x; 6.6929x over previous
//
#include <hip/hip_runtime.h>

typedef __fp16 f16x2 __attribute__((ext_vector_type(2)));

#define Dm 128
#define Bn 16
#define TZ 4            // tile depth
#define TYt 8           // tile height
#define TXv 16          // tile width in voxels (8 pairs)
#define HZ 6            // halo depth rows
#define HY 10           // halo height rows
#define HX 18           // valid halo width (words)
#define HXP 24          // LDS row stride (words)
#define TILE_A 1536     // padded slab words (64 rows x 24)
#define NT 256
#define NLOAD (TILE_A / NT)   // 6
#define VOX (Dm * Dm * Dm)
#define BCH 2
#define NCH (Bn / BCH)

__device__ __forceinline__ void gload_lds4(const void* g, void* l) {
  __builtin_amdgcn_global_load_lds(
      (const __attribute__((address_space(1))) void*)g,
      (__attribute__((address_space(3))) void*)l,
      4, 0, 0);
}
__device__ __forceinline__ int iclamp(int v, int lo, int hi) {
  return v < lo ? lo : (v > hi ? hi : v);
}
__device__ __forceinline__ f16x2 pkrtz(float lo, float hi) {
  return __builtin_amdgcn_cvt_pkrtz(lo, hi);
}
// h12 = (h01.hi, h23.lo): middle overlapping pair via byte-perm
__device__ __forceinline__ f16x2 midpair(f16x2 h23, f16x2 h01) {
  unsigned r = __builtin_amdgcn_perm(__builtin_bit_cast(unsigned, h23),
                                     __builtin_bit_cast(unsigned, h01),
                                     0x05040302u);
  return __builtin_bit_cast(f16x2, r);
}

extern "C" __global__ void __launch_bounds__(NT, 4)   // VGPR cap 128 (no spill risk)
fused3d(const float* __restrict__ img, const float* __restrict__ x,
        const float* __restrict__ Wf, const float* __restrict__ bfp,
        float* __restrict__ out)
{
  __shared__ float sImg[TILE_A];            // 6 KiB
  __shared__ float sX[2][BCH][TILE_A];      // 24 KiB

  const int tid = threadIdx.x;
  const int tx = tid & 7;          // w-pair 0..7
  const int ty = (tid >> 3) & 7;   // h 0..7
  const int tz = tid >> 6;         // d 0..3 (wave id)

  // T1 XCD swizzle: each XCD gets a contiguous slab of 512 spatial tiles
  const int bid = blockIdx.x;                  // 0..4095
  const int s  = (bid & 7) * 512 + (bid >> 3);
  const int bx = s & 7, by = (s >> 3) & 15, bz = s >> 7;
  const int w0 = bx * TXv, h0 = by * TYt, d0 = bz * TZ;

  // staging map: LDS slot i <-> clamped global voxel (identical for img and x)
  int goff[NLOAD]; bool gin[NLOAD];
#pragma unroll
  for (int k = 0; k < NLOAD; ++k) {
    int i  = tid + k * NT;          // 0..1535
    int r  = i / HXP;
    int c  = i - r * HXP;           // 0..23 (c>=18 pad)
    int zz = r / HY;                // 0..6 (zz==6 pad rows)
    int yy = r - zz * HY;
    int gd = d0 + zz - 1, gh = h0 + yy - 1, gw = w0 + c - 1;
    gin[k]  = (zz < HZ) & (c < HX) &
              ((unsigned)gd < Dm) & ((unsigned)gh < Dm) & ((unsigned)gw < Dm);
    goff[k] = (iclamp(gd, 0, Dm - 1) * Dm + iclamp(gh, 0, Dm - 1)) * Dm
              + iclamp(gw, 0, Dm - 1);
  }

  // zero image LDS (conv SAME zero-pad); x needs no zeroing (clamp+tap-mask)
#pragma unroll
  for (int k = 0; k < NLOAD; ++k) sImg[tid + k * NT] = 0.f;
  __syncthreads();

  const int wbase = tid & ~63;
  // stage image (masked: OOB stays zero) + x chunk 0 (clamped, unconditional)
#pragma unroll
  for (int k = 0; k < NLOAD; ++k)
    if (gin[k]) gload_lds4(img + goff[k], &sImg[k * NT + wbase]);
#pragma unroll
  for (int j = 0; j < BCH; ++j) {
    const float* xb = x + (size_t)j * VOX;
#pragma unroll
    for (int k = 0; k < NLOAD; ++k)
      gload_lds4(xb + goff[k], &sX[0][j][k * NT + wbase]);
  }
  __syncthreads();   // sImg + chunk 0 staged & drained

  const int od = d0 + tz, oh = h0 + ty, ow = w0 + 2 * tx;
  const int tbase = (tz * HY + ty) * HXP + 2 * tx;

  // ---- K-gen, 9 chunks x 3 taps: 6 fp32 accs peak; result packed fp16 pairs.
  // Boundary tap-masks baked in (x zero-pad semantics).
  f16x2 K2[27];
#pragma unroll
  for (int oc = 0; oc < 9; ++oc) {
    float a0[3], a1[3];
#pragma unroll
    for (int q = 0; q < 3; ++q) { float bb = bfp[oc * 3 + q]; a0[q] = bb; a1[q] = bb; }
#pragma unroll
    for (int rr = 0; rr < 9; ++rr) {
      const int base = tbase + ((rr / 3) * HY + (rr % 3)) * HXP;
      float2 a  = *(const float2*)&sImg[base];
      float2 b2 = *(const float2*)&sImg[base + 2];
#pragma unroll
      for (int q = 0; q < 3; ++q) {
        const int o = oc * 3 + q;
        const float wa = Wf[o * 27 + rr * 3 + 0];
        const float wb = Wf[o * 27 + rr * 3 + 1];
        const float wc = Wf[o * 27 + rr * 3 + 2];
        a0[q] = fmaf(wa, a.x, fmaf(wb, a.y,  fmaf(wc, b2.x, a0[q])));
        a1[q] = fmaf(wa, a.y, fmaf(wb, b2.x, fmaf(wc, b2.y, a1[q])));
      }
    }
#pragma unroll
    for (int q = 0; q < 3; ++q) {
      const int o = oc * 3 + q;
      const int di = o / 9, dj = (o / 3) % 3, dk = o % 3;
      const bool mm = ((unsigned)(od + di - 1) < Dm) & ((unsigned)(oh + dj - 1) < Dm);
      const float m0 = (mm & ((unsigned)(ow + dk - 1) < Dm)) ? 1.f : 0.f;
      const float m1 = (mm & ((unsigned)(ow + dk)     < Dm)) ? 1.f : 0.f;
      K2[o] = pkrtz(a0[q] * m0, a1[q] * m1);
    }
  }

  const size_t obase = (((size_t)od) * Dm + oh) * Dm + ow;

  // ---- batch loop: 8 chunks x 2 batches, prefetch-first, pk-fp16 apply
  for (int ch = 0; ch < NCH; ++ch) {
    const int cur = ch & 1;
    if (ch + 1 < NCH) {
      const float* xc = x + (size_t)(ch + 1) * BCH * VOX;
#pragma unroll
      for (int j = 0; j < BCH; ++j) {
        const float* xb = xc + (size_t)j * VOX;
#pragma unroll
        for (int k = 0; k < NLOAD; ++k)
          gload_lds4(xb + goff[k], &sX[cur ^ 1][j][k * NT + wbase]);
      }
    }

#pragma unroll
    for (int j = 0; j < BCH; ++j) {
      const float* sxb = sX[cur][j];
      f16x2 accA = {(__fp16)0.f, (__fp16)0.f};
      f16x2 accB = {(__fp16)0.f, (__fp16)0.f};
#pragma unroll
      for (int rr = 0; rr < 9; ++rr) {
        const int base = tbase + ((rr / 3) * HY + (rr % 3)) * HXP;
        float2 a  = *(const float2*)&sxb[base];
        float2 b2 = *(const float2*)&sxb[base + 2];
        f16x2 h01 = pkrtz(a.x, a.y);      // (x[-1], x0)
        f16x2 h23 = pkrtz(b2.x, b2.y);    // (x1, x2)
        f16x2 h12 = midpair(h23, h01);    // (x0, x1)
        if (rr & 1) {
          accB = __builtin_elementwise_fma(K2[rr * 3 + 0], h01, accB);
          accB = __builtin_elementwise_fma(K2[rr * 3 + 1], h12, accB);
          accB = __builtin_elementwise_fma(K2[rr * 3 + 2], h23, accB);
        } else {
          accA = __builtin_elementwise_fma(K2[rr * 3 + 0], h01, accA);
          accA = __builtin_elementwise_fma(K2[rr * 3 + 1], h12, accA);
          accA = __builtin_elementwise_fma(K2[rr * 3 + 2], h23, accA);
        }
      }
      f16x2 acc = accA + accB;
      float2 st; st.x = (float)acc.x; st.y = (float)acc.y;
      *(float2*)&out[(size_t)(ch * BCH + j) * VOX + obase] = st;
    }

    __syncthreads();  // prefetched chunk complete + guards buffer reuse
  }
}

extern "C" void kernel_launch(void* const* d_in, const int* in_sizes, int n_in,
                              void* d_out, int out_size, void* d_ws, size_t ws_size,
                              hipStream_t stream) {
  const float* img = (const float*)d_in[0];
  const float* x   = (const float*)d_in[1];
  const float* Wf  = (const float*)d_in[2];
  const float* bf  = (const float*)d_in[3];
  float* out = (float*)d_out;
  // grid: 8(w) x 16(h) x 32(d) = 4096 tiles, 1-D for XCD swizzle
  hipLaunchKernelGGL(fused3d, dim3(4096), dim3(NT), 0, stream, img, x, Wf, bf, out);
}